// Round 15
// baseline (16.294 us; speedup 1.0000x reference)
//
#include <hip/hip_runtime.h>

// NQ=8, NL=3, B=65536 — fused single kernel, barrier-free phase A.
// Grid 256 blocks x 576 thr (9 waves). Wave wv owns COLUMN wv of C = U*P:
// lane l, reg r in [0,4) holds basis b = r*64+l. Bits 7,6 of b are r bits ->
// register-local RY pairs; bits 5..0 -> in-wave lane_xor (DPP/swizzle).
// RZZ diag = product of precomputed half-angle phase factors (no sincos,
// no LDS). Phase A: ZERO barriers, ZERO LDS (was 6+ barriers, 3 round-trips).
// Then: 1 restage barrier -> R12's phase B (WHT in a DISJOINT LDS region,
// saving another barrier) -> combine -> R12-style low-VGPR eval.
// Barriers total: 4 (was 12).

#define ROW 92   // padded row: A@0(9) d1@12(16) d2@28(14) d3@44(12)
                 // d4@56(10) d5@68(8) d6@76(6) d7@84(4) d8@88(2)

template <int CTRL>
__device__ __forceinline__ float dppf(float x) {
    return __int_as_float(
        __builtin_amdgcn_mov_dpp(__float_as_int(x), CTRL, 0xF, 0xF, true));
}
template <int PAT>
__device__ __forceinline__ float swzp(float x) {
    return __int_as_float(__builtin_amdgcn_ds_swizzle(__float_as_int(x), PAT));
}
template <int B>
__device__ __forceinline__ float lane_xor(float x) {
    if constexpr (B == 0) return dppf<0xB1>(x);        // quad_perm xor1
    else if constexpr (B == 1) return dppf<0x4E>(x);   // quad_perm xor2
    else if constexpr (B == 2) return swzp<0x101F>(x); // ds_swizzle xor4
    else if constexpr (B == 3) return dppf<0x128>(x);  // row_ror:8 == xor8
    else if constexpr (B == 4) return swzp<0x401F>(x); // ds_swizzle xor16
    else return __shfl_xor(x, 32, 64);                 // xor32
}

__device__ __forceinline__ float2 cmul(float2 a, float2 b) {
    return make_float2(a.x * b.x - a.y * b.y, a.x * b.y + a.y * b.x);
}

// RY on a lane-bit wire: partner via lane_xor, all 4 regs
template <int B>
__device__ __forceinline__ void gate_lane(float2 CA[4], float2 cs, int lane) {
    const float sg = ((lane >> B) & 1) ? cs.y : -cs.y;
    #pragma unroll
    for (int r = 0; r < 4; ++r) {
        const float px = lane_xor<B>(CA[r].x);
        const float py = lane_xor<B>(CA[r].y);
        CA[r].x = cs.x * CA[r].x + sg * px;
        CA[r].y = cs.x * CA[r].y + sg * py;
    }
}
// RY on a register-bit wire: a0 = bit0 element, a1 = bit1 element
__device__ __forceinline__ void gate_pair(float2& a0, float2& a1, float2 cs) {
    const float2 t0 = make_float2(cs.x * a0.x - cs.y * a1.x,
                                  cs.x * a0.y - cs.y * a1.y);
    const float2 t1 = make_float2(cs.y * a0.x + cs.x * a1.x,
                                  cs.y * a0.y + cs.x * a1.y);
    a0 = t0; a1 = t1;
}

template <int N>
__device__ __forceinline__ void wht_chunk(float (&v)[N], float* buf,
                                          int lane, int wvg, int row, int base) {
    #define WHT_LVL(B)                                                   \
    {                                                                    \
        const float sgn = ((lane >> (B)) & 1) ? -1.f : 1.f;              \
        _Pragma("unroll")                                                \
        for (int i = 0; i < N; ++i) {                                    \
            const float p = lane_xor<B>(v[i]);                           \
            v[i] = fmaf(sgn, v[i], p);                                   \
        }                                                                \
    }
    WHT_LVL(0) WHT_LVL(1) WHT_LVL(2) WHT_LVL(3) WHT_LVL(4) WHT_LVL(5)
    #undef WHT_LVL
    if (row >= 0) {
        #pragma unroll
        for (int i = 0; i < N; ++i) buf[(wvg * 7 + row) * 81 + base + i] = v[i];
    }
}

template <int D, int N>
__device__ __forceinline__ void fill_pairs(const float2 (&C9)[9], float (&c)[N],
                                           int off) {
    #pragma unroll
    for (int k = 0; k + D <= 8; ++k) {
        const float2 hi = C9[k + D], lo = C9[k];
        c[off + 2 * k]     = 2.f * (hi.x * lo.x + hi.y * lo.y);
        c[off + 2 * k + 1] = 2.f * (hi.y * lo.x - hi.x * lo.y);
    }
}

__device__ __forceinline__ void prep(float z1v, float z2v, float& u, float& w8,
                                     float Tr[9], float Ti[9]) {
    const float u1 = sqrtf(fmaxf(0.f, 1.f - z1v * z1v));   // cos a1
    const float q1 = 0.5f * (1.f + u1);                     // cos^2(a1/2)
    const float s1 = copysignf(sqrtf(fmaxf(0.f, 0.5f * (1.f - u1))), z1v);
    const float tn = s1 * rsqrtf(q1);                       // tan(a1/2)
    const float u2 = sqrtf(fmaxf(0.f, 1.f - z2v * z2v));    // cos a2
    const float tr = tn * u2, ti = tn * z2v;                // t = tn e^{i a2}
    u = tn * tn;
    w8 = q1 * q1; w8 *= w8; w8 *= w8;                       // q1^8
    Tr[1] = tr; Ti[1] = ti;
    #pragma unroll
    for (int d = 2; d <= 8; ++d) {
        Tr[d] = Tr[d - 1] * tr - Ti[d - 1] * ti;
        Ti[d] = Tr[d - 1] * ti + Ti[d - 1] * tr;
    }
}

__device__ __forceinline__ float apoly1(const float* gp, float u) {
    const float4 c0 = ((const float4*)gp)[0];
    const float4 c1 = ((const float4*)gp)[1];
    const float4 c2 = ((const float4*)gp)[2];
    const float a[9] = {c0.x, c0.y, c0.z, c0.w, c1.x, c1.y, c1.z, c1.w, c2.x};
    float r = a[8];
    #pragma unroll
    for (int m = 7; m >= 0; --m) r = fmaf(r, u, a[m]);
    return r;
}

template <int NP>
__device__ __forceinline__ float2 bpoly1(const float* gp, float u) {
    constexpr int NF4 = (2 * NP + 3) / 4;
    float4 c[NF4];
    const float4* p = (const float4*)gp;
    #pragma unroll
    for (int i = 0; i < NF4; ++i) c[i] = p[i];
    float br = 0.f, bi = 0.f;
    #pragma unroll
    for (int k = NP - 1; k >= 0; --k) {
        const float re = (k & 1) ? c[k >> 1].z : c[k >> 1].x;
        const float im = (k & 1) ? c[k >> 1].w : c[k >> 1].y;
        br = fmaf(br, u, re);
        bi = fmaf(bi, u, im);
    }
    return make_float2(br, bi);
}

__global__ __launch_bounds__(576, 3)
void qsim_fused(const float* __restrict__ w, const float* __restrict__ z1,
                const float* __restrict__ z2, float* __restrict__ out,
                int nsamp) {
    __shared__ float2 xchC[9][256];             // 18432 B: evolved columns
    __shared__ float wht[2 * 28 * 81];          // 18144 B: WHT rows (disjoint)
    __shared__ float2 s_cs[3][15];              // (cos,sin) of w/2, all 15
    __shared__ __align__(16) float g[8 * ROW];  // 2944 B: padded coeff rows

    const int t = threadIdx.x;
    const int lane = t & 63;
    const int wv = t >> 6;            // 0..8 — owned column
    const int j = t & 255;            // basis / sample slot (t < 512)
    const int h = (t >> 8) & 1;       // component/qubit group (t < 512)
    const int M0 = h * 4;

    // hoisted eval inputs
    const int s = blockIdx.x * 256 + j;
    const bool ev = (t < 512) && (s < nsamp);
    const float z1v = ev ? z1[s] : 0.f;
    const float z2v = ev ? z2[s] : 0.f;

    if (t < 45) {
        const int l = t / 15, i = t - 15 * l;
        const float a = 0.5f * w[l * 15 + i];
        s_cs[l][i] = make_float2(__cosf(a), __sinf(a));
    }
    __syncthreads();                                        // barrier 1

    // ---- phase A (barrier-free): wave wv evolves column wv
    float2 CA[4];
    const int pl = __popc(lane);
    #pragma unroll
    for (int r = 0; r < 4; ++r)
        CA[r] = make_float2((pl + (r >> 1) + (r & 1) == wv) ? 1.f : 0.f, 0.f);

    #pragma unroll 1
    for (int l = 0; l < 3; ++l) {
        gate_pair(CA[0], CA[2], s_cs[l][0]);   // wire 0 <-> bit 7 (reg)
        gate_pair(CA[1], CA[3], s_cs[l][0]);
        gate_pair(CA[0], CA[1], s_cs[l][1]);   // wire 1 <-> bit 6 (reg)
        gate_pair(CA[2], CA[3], s_cs[l][1]);
        gate_lane<5>(CA, s_cs[l][2], lane);    // wires 2..7 <-> lane bits 5..0
        gate_lane<4>(CA, s_cs[l][3], lane);
        gate_lane<3>(CA, s_cs[l][4], lane);
        gate_lane<2>(CA, s_cs[l][5], lane);
        gate_lane<1>(CA, s_cs[l][6], lane);
        gate_lane<0>(CA, s_cs[l][7], lane);
        if (l < 2) {   // RZZ diag = Pi exp(-i w_i zz_i / 2), factor products
            // lane-only factors: i=2..6 use bits (7-i),(6-i) = lane bits
            float2 base = make_float2(1.f, 0.f);
            #pragma unroll
            for (int i = 2; i <= 6; ++i) {
                const float2 cz = s_cs[l][8 + i];
                const int d = ((lane >> (7 - i)) ^ (lane >> (6 - i))) & 1;
                base = cmul(base, make_float2(cz.x, d ? cz.y : -cz.y));
            }
            const float2 cz0 = s_cs[l][8];     // i=0: bits 7,6 = r bits
            const float2 cz1 = s_cs[l][9];     // i=1: bits 6,5 = r0, lane5
            const int l5 = (lane >> 5) & 1;
            #pragma unroll
            for (int r = 0; r < 4; ++r) {
                const int d0 = ((r >> 1) ^ (r & 1)) & 1;
                const int d1 = (r & 1) ^ l5;
                float2 ph = cmul(base, make_float2(cz0.x, d0 ? cz0.y : -cz0.y));
                ph = cmul(ph, make_float2(cz1.x, d1 ? cz1.y : -cz1.y));
                CA[r] = cmul(CA[r], ph);
            }
        }
    }

    // ---- restage: wave wv writes its column; then all read full rows
    #pragma unroll
    for (int r = 0; r < 4; ++r) xchC[wv][r * 64 + lane] = CA[r];
    __syncthreads();                                        // barrier 2

    // ---- phase B (t < 512): products + chunked WHT into DISJOINT wht buf
    const int wvg = (t >> 6) & 3;
    if (t < 512) {
        float2 C9[9];
        #pragma unroll
        for (int m = 0; m < 9; ++m) C9[m] = xchC[m][j];
        float* buf = wht + h * (28 * 81);
        const int row = (lane == 0) ? 0 : (lane == 1) ? 1 : (lane == 2) ? 2 :
                        (lane == 4) ? 3 : (lane == 8) ? 4 : (lane == 16) ? 5 :
                        (lane == 32) ? 6 : -1;
        if (h == 0) {                // components 0..38: diag, d=1, d=2
            {   float c[9];
                #pragma unroll
                for (int m = 0; m < 9; ++m)
                    c[m] = C9[m].x * C9[m].x + C9[m].y * C9[m].y;
                wht_chunk(c, buf, lane, wvg, row, 0);
            }
            { float c[16]; fill_pairs<1>(C9, c, 0); wht_chunk(c, buf, lane, wvg, row, 9);  }
            { float c[14]; fill_pairs<2>(C9, c, 0); wht_chunk(c, buf, lane, wvg, row, 25); }
        } else {                     // components 39..80: d=3..8
            { float c[12]; fill_pairs<3>(C9, c, 0); wht_chunk(c, buf, lane, wvg, row, 39); }
            { float c[10]; fill_pairs<4>(C9, c, 0); wht_chunk(c, buf, lane, wvg, row, 51); }
            { float c[8];  fill_pairs<5>(C9, c, 0); wht_chunk(c, buf, lane, wvg, row, 61); }
            {   float c[12];
                fill_pairs<6>(C9, c, 0);
                fill_pairs<7>(C9, c, 6);
                fill_pairs<8>(C9, c, 10);
                wht_chunk(c, buf, lane, wvg, row, 69);
            }
        }
    }
    __syncthreads();                                        // barrier 3

    // ---- cross-wave combine into padded rows; qubit q <-> idx bit b = 7-q
    for (int o = t; o < 648; o += 576) {
        const int q = o / 81, i = o - 81 * q;
        const int b = 7 - q;
        const float* gb = wht + ((i < 39) ? 0 : 28 * 81);
        float r;
        if (b < 6) {
            const int rw = b + 1;
            r = gb[(0 * 7 + rw) * 81 + i] + gb[(1 * 7 + rw) * 81 + i] +
                gb[(2 * 7 + rw) * 81 + i] + gb[(3 * 7 + rw) * 81 + i];
        } else if (b == 6) {
            r = gb[(0 * 7) * 81 + i] - gb[(1 * 7) * 81 + i] +
                gb[(2 * 7) * 81 + i] - gb[(3 * 7) * 81 + i];
        } else {
            r = gb[(0 * 7) * 81 + i] + gb[(1 * 7) * 81 + i] -
                gb[(2 * 7) * 81 + i] - gb[(3 * 7) * 81 + i];
        }
        const int off = i + ((i < 9) ? 0 : (i < 39) ? 3 : (i < 61) ? 5 :
                             (i < 75) ? 7 : 9);
        g[q * ROW + off] = r;
    }
    __syncthreads();                                        // barrier 4

    // ---- phase C: thread (j,h) evaluates sample s, qubits [M0, M0+4)
    if (!ev) return;

    float u, w8;
    float Tr[9], Ti[9];
    prep(z1v, z2v, u, w8, Tr, Ti);

    float o4[4];
    #pragma unroll
    for (int k = 0; k < 4; ++k) {
        const float* gq = g + (M0 + k) * ROW;
        float r = apoly1(gq, u);
        #define DTERM(D, NP, OFF)                                        \
        {                                                                \
            const float2 b = bpoly1<NP>(gq + OFF, u);                    \
            r = fmaf(Tr[D], b.x, r);                                     \
            r = fmaf(-Ti[D], b.y, r);                                    \
        }
        DTERM(1, 8, 12) DTERM(2, 7, 28) DTERM(3, 6, 44) DTERM(4, 5, 56)
        DTERM(5, 4, 68) DTERM(6, 3, 76) DTERM(7, 2, 84) DTERM(8, 1, 88)
        #undef DTERM
        o4[k] = w8 * r;
    }

    float4* op = (float4*)(out + (size_t)s * 8 + M0);
    *op = make_float4(o4[0], o4[1], o4[2], o4[3]);
}

extern "C" void kernel_launch(void* const* d_in, const int* in_sizes, int n_in,
                              void* d_out, int out_size, void* d_ws,
                              size_t ws_size, hipStream_t stream) {
    const float* w  = (const float*)d_in[0];   // (3, 15) f32
    const float* z1 = (const float*)d_in[1];   // (B,)   f32
    const float* z2 = (const float*)d_in[2];   // (B,)   f32
    float* out = (float*)d_out;                // (B, 8) f32

    const int n = in_sizes[1];
    qsim_fused<<<(n + 255) / 256, 576, 0, stream>>>(w, z1, z2, out, n);
}